// Round 1
// baseline (3525.740 us; speedup 1.0000x reference)
//
#include <hip/hip_runtime.h>

// Problem constants
// B=4, H=W=64, N=4096, C=512, HEAD=8, dh=64, SR=4, Nk=256

// ---------------- weight prep: WqT, WpT, WkvT (=[Wk^T | Wv^T]) ----------------
__global__ void prep_weights_kernel(const float* __restrict__ Wq,
                                    const float* __restrict__ Wk,
                                    const float* __restrict__ Wv,
                                    const float* __restrict__ Wp,
                                    float* __restrict__ WqT,
                                    float* __restrict__ WpT,
                                    float* __restrict__ WkvT) {
  __shared__ float t[32][33];
  int z = blockIdx.z;
  const float* src = (z == 0) ? Wq : (z == 1) ? Wp : (z == 2) ? Wk : Wv;
  int n0 = blockIdx.y * 32, k0 = blockIdx.x * 32;
  int tx = threadIdx.x, ty = threadIdx.y;  // 32 x 8
#pragma unroll
  for (int i = 0; i < 32; i += 8)
    t[ty + i][tx] = src[(size_t)(n0 + ty + i) * 512 + k0 + tx];
  __syncthreads();
  float* dst = (z == 0) ? WqT : (z == 1) ? WpT : WkvT;
  int stride = (z < 2) ? 512 : 1024;
  int off = (z == 3) ? 512 : 0;
#pragma unroll
  for (int i = 0; i < 32; i += 8)
    dst[(size_t)(k0 + ty + i) * stride + off + n0 + tx] = t[tx][ty + i];
}

__global__ void concat_bias_kernel(const float* __restrict__ bk,
                                   const float* __restrict__ bv,
                                   float* __restrict__ bkv) {
  int t = threadIdx.x;  // 512
  bkv[t] = bk[t];
  bkv[512 + t] = bv[t];
}

// ---------------- fp32 SGEMM, 128x128 tile, BK=16, 256 thr, 8x8 micro ----------------
__global__ __launch_bounds__(256) void sgemm128_kernel(
    const float* __restrict__ A, const float* __restrict__ B,
    const float* __restrict__ bias, float* __restrict__ C,
    int M, int N, int K) {
  __shared__ __align__(16) float As[16][132];  // [k][m], padded
  __shared__ __align__(16) float Bs[16][128];  // [k][n]
  int tid = threadIdx.x;
  int bx = blockIdx.x, by = blockIdx.y;
  int tx = tid & 15, ty = tid >> 4;
  float acc[2][2][4][4] = {};
  for (int k0 = 0; k0 < K; k0 += 16) {
#pragma unroll
    for (int i = 0; i < 2; ++i) {
      int idx = tid + i * 256;
      int m = idx >> 2, kq = (idx & 3) << 2;
      float4 a = *(const float4*)(A + (size_t)(by * 128 + m) * K + k0 + kq);
      As[kq + 0][m] = a.x; As[kq + 1][m] = a.y;
      As[kq + 2][m] = a.z; As[kq + 3][m] = a.w;
    }
#pragma unroll
    for (int i = 0; i < 2; ++i) {
      int idx = tid + i * 256;
      int k = idx >> 5, n4 = (idx & 31) << 2;
      *(float4*)&Bs[k][n4] = *(const float4*)(B + (size_t)(k0 + k) * N + bx * 128 + n4);
    }
    __syncthreads();
#pragma unroll
    for (int k = 0; k < 16; ++k) {
      float4 a0 = *(float4*)&As[k][ty * 4];
      float4 a1 = *(float4*)&As[k][64 + ty * 4];
      float4 b0 = *(float4*)&Bs[k][tx * 4];
      float4 b1 = *(float4*)&Bs[k][64 + tx * 4];
      float av[2][4] = {{a0.x, a0.y, a0.z, a0.w}, {a1.x, a1.y, a1.z, a1.w}};
      float bv[2][4] = {{b0.x, b0.y, b0.z, b0.w}, {b1.x, b1.y, b1.z, b1.w}};
#pragma unroll
      for (int qr = 0; qr < 2; ++qr)
#pragma unroll
        for (int i = 0; i < 4; ++i)
#pragma unroll
          for (int qc = 0; qc < 2; ++qc)
#pragma unroll
            for (int j = 0; j < 4; ++j)
              acc[qr][qc][i][j] += av[qr][i] * bv[qc][j];
    }
    __syncthreads();
  }
#pragma unroll
  for (int qr = 0; qr < 2; ++qr)
#pragma unroll
    for (int i = 0; i < 4; ++i) {
      int row = by * 128 + qr * 64 + ty * 4 + i;
#pragma unroll
      for (int qc = 0; qc < 2; ++qc) {
        int col = bx * 128 + qc * 64 + tx * 4;
        float4 bb = *(const float4*)(bias + col);
        float4 o;
        o.x = acc[qr][qc][i][0] + bb.x;
        o.y = acc[qr][qc][i][1] + bb.y;
        o.z = acc[qr][qc][i][2] + bb.z;
        o.w = acc[qr][qc][i][3] + bb.w;
        *(float4*)(C + (size_t)row * N + col) = o;
      }
    }
}

// ---------------- fp32 SGEMM, 64x64 tile (for the small K/V projection) ----------------
__global__ __launch_bounds__(256) void sgemm64_kernel(
    const float* __restrict__ A, const float* __restrict__ B,
    const float* __restrict__ bias, float* __restrict__ C,
    int M, int N, int K) {
  __shared__ __align__(16) float As[16][68];
  __shared__ __align__(16) float Bs[16][64];
  int tid = threadIdx.x;
  int bx = blockIdx.x, by = blockIdx.y;
  int tx = tid & 15, ty = tid >> 4;
  float acc[4][4] = {};
  for (int k0 = 0; k0 < K; k0 += 16) {
    {
      int m = tid >> 2, kq = (tid & 3) << 2;
      float4 a = *(const float4*)(A + (size_t)(by * 64 + m) * K + k0 + kq);
      As[kq + 0][m] = a.x; As[kq + 1][m] = a.y;
      As[kq + 2][m] = a.z; As[kq + 3][m] = a.w;
    }
    {
      int k = tid >> 4, n4 = (tid & 15) << 2;
      *(float4*)&Bs[k][n4] = *(const float4*)(B + (size_t)(k0 + k) * N + bx * 64 + n4);
    }
    __syncthreads();
#pragma unroll
    for (int k = 0; k < 16; ++k) {
      float4 a0 = *(float4*)&As[k][ty * 4];
      float4 b0 = *(float4*)&Bs[k][tx * 4];
      float av[4] = {a0.x, a0.y, a0.z, a0.w};
      float bv[4] = {b0.x, b0.y, b0.z, b0.w};
#pragma unroll
      for (int i = 0; i < 4; ++i)
#pragma unroll
        for (int j = 0; j < 4; ++j) acc[i][j] += av[i] * bv[j];
    }
    __syncthreads();
  }
#pragma unroll
  for (int i = 0; i < 4; ++i) {
    int row = by * 64 + ty * 4 + i;
    int col = bx * 64 + tx * 4;
    float4 bb = *(const float4*)(bias + col);
    float4 o;
    o.x = acc[i][0] + bb.x; o.y = acc[i][1] + bb.y;
    o.z = acc[i][2] + bb.z; o.w = acc[i][3] + bb.w;
    *(float4*)(C + (size_t)row * N + col) = o;
  }
}

// ---------------- conv as split-K GEMM: one (kh,kw) chunk per blockIdx.z ----------------
// M=1024 patches, K=512 (ci), N=512 (co). Writes partials [16][1024][512].
__global__ __launch_bounds__(256) void conv_gemm_kernel(
    const float* __restrict__ x, const float* __restrict__ Wsr,
    float* __restrict__ part) {
  __shared__ __align__(16) float As[16][132];
  __shared__ __align__(16) float Bs[16][128];
  int tid = threadIdx.x;
  int bx = blockIdx.x, by = blockIdx.y, z = blockIdx.z;
  int kh = z >> 2, kw = z & 3;
  int tx = tid & 15, ty = tid >> 4;
  int ml[2];
  size_t abase[2];
#pragma unroll
  for (int i = 0; i < 2; ++i) {
    int idx = tid + i * 256;
    int m = idx >> 2;
    int gm = by * 128 + m;
    int b = gm >> 8, rem = gm & 255, oh = rem >> 4, ow = rem & 15;
    abase[i] = (size_t)(b * 4096 + (oh * 4 + kh) * 64 + ow * 4 + kw) * 512;
    ml[i] = m;
  }
  const float* Wbase = Wsr + (size_t)z * 512 * 512;
  float acc[2][2][4][4] = {};
  for (int k0 = 0; k0 < 512; k0 += 16) {
#pragma unroll
    for (int i = 0; i < 2; ++i) {
      int idx = tid + i * 256;
      int kq = (idx & 3) << 2;
      float4 a = *(const float4*)(x + abase[i] + k0 + kq);
      As[kq + 0][ml[i]] = a.x; As[kq + 1][ml[i]] = a.y;
      As[kq + 2][ml[i]] = a.z; As[kq + 3][ml[i]] = a.w;
    }
#pragma unroll
    for (int i = 0; i < 2; ++i) {
      int idx = tid + i * 256;
      int k = idx >> 5, n4 = (idx & 31) << 2;
      *(float4*)&Bs[k][n4] =
          *(const float4*)(Wbase + (size_t)(k0 + k) * 512 + bx * 128 + n4);
    }
    __syncthreads();
#pragma unroll
    for (int k = 0; k < 16; ++k) {
      float4 a0 = *(float4*)&As[k][ty * 4];
      float4 a1 = *(float4*)&As[k][64 + ty * 4];
      float4 b0 = *(float4*)&Bs[k][tx * 4];
      float4 b1 = *(float4*)&Bs[k][64 + tx * 4];
      float av[2][4] = {{a0.x, a0.y, a0.z, a0.w}, {a1.x, a1.y, a1.z, a1.w}};
      float bv[2][4] = {{b0.x, b0.y, b0.z, b0.w}, {b1.x, b1.y, b1.z, b1.w}};
#pragma unroll
      for (int qr = 0; qr < 2; ++qr)
#pragma unroll
        for (int i = 0; i < 4; ++i)
#pragma unroll
          for (int qc = 0; qc < 2; ++qc)
#pragma unroll
            for (int j = 0; j < 4; ++j)
              acc[qr][qc][i][j] += av[qr][i] * bv[qc][j];
    }
    __syncthreads();
  }
  float* Cp = part + (size_t)z * 1024 * 512;
#pragma unroll
  for (int qr = 0; qr < 2; ++qr)
#pragma unroll
    for (int i = 0; i < 4; ++i) {
      int row = by * 128 + qr * 64 + ty * 4 + i;
#pragma unroll
      for (int qc = 0; qc < 2; ++qc) {
        int col = bx * 128 + qc * 64 + tx * 4;
        float4 o;
        o.x = acc[qr][qc][i][0]; o.y = acc[qr][qc][i][1];
        o.z = acc[qr][qc][i][2]; o.w = acc[qr][qc][i][3];
        *(float4*)(Cp + (size_t)row * 512 + col) = o;
      }
    }
}

// ---------------- partial-sum + bias + LayerNorm ----------------
__global__ __launch_bounds__(256) void ln_kernel(
    const float* __restrict__ part, const float* __restrict__ bsr,
    const float* __restrict__ gamma, const float* __restrict__ beta,
    float* __restrict__ xkv) {
  int row = blockIdx.x;  // 0..1023
  int t = threadIdx.x;   // 256
  float v0 = bsr[t], v1 = bsr[t + 256];
  for (int p = 0; p < 16; ++p) {
    v0 += part[(size_t)p * 524288 + (size_t)row * 512 + t];
    v1 += part[(size_t)p * 524288 + (size_t)row * 512 + t + 256];
  }
  float s = v0 + v1, sq = v0 * v0 + v1 * v1;
#pragma unroll
  for (int o = 1; o < 64; o <<= 1) {
    s += __shfl_xor(s, o);
    sq += __shfl_xor(sq, o);
  }
  __shared__ float red[8];
  int wv = t >> 6;
  if ((t & 63) == 0) { red[wv] = s; red[4 + wv] = sq; }
  __syncthreads();
  s = red[0] + red[1] + red[2] + red[3];
  sq = red[4] + red[5] + red[6] + red[7];
  float mu = s * (1.0f / 512.0f);
  float var = sq * (1.0f / 512.0f) - mu * mu;
  float rs = rsqrtf(var + 1e-5f);
  xkv[(size_t)row * 512 + t] = (v0 - mu) * rs * gamma[t] + beta[t];
  xkv[(size_t)row * 512 + t + 256] = (v1 - mu) * rs * gamma[t + 256] + beta[t + 256];
}

// ---------------- fused attention: one block = (b, h, 32 q-rows) ----------------
// kv layout: [B][Nk=256][1024] with cols 0..511 = K-proj, 512..1023 = V-proj.
__global__ __launch_bounds__(256) void attn_kernel(
    const float* __restrict__ q, const float* __restrict__ kv,
    float* __restrict__ out) {
  __shared__ __align__(16) float tile[128 * 65];  // K or V tile, stride 65 (bank-safe)
  __shared__ __align__(16) float qs[32 * 64];
  int tid = threadIdx.x;
  int qt = blockIdx.x, h = blockIdx.y, b = blockIdx.z;
  int r = tid >> 3, g = tid & 7;
  int n0 = qt * 32;
  // load q tile [32][64]
#pragma unroll
  for (int i = 0; i < 2; ++i) {
    int idx = tid + i * 256;
    int rr = idx >> 4, d4 = (idx & 15) << 2;
    *(float4*)&qs[rr * 64 + d4] =
        *(const float4*)(q + (size_t)(b * 4096 + n0 + rr) * 512 + h * 64 + d4);
  }
  __syncthreads();
  float qreg[64];
#pragma unroll
  for (int d = 0; d < 64; ++d) qreg[d] = qs[r * 64 + d];

  float s[32];
  float mx = -1e30f;
#pragma unroll
  for (int t = 0; t < 2; ++t) {
    // load K tile (rows t*128 .. t*128+127)
#pragma unroll
    for (int i = 0; i < 8; ++i) {
      int idx = tid + i * 256;
      int row = idx >> 4, d4 = (idx & 15) << 2;
      float4 v = *(const float4*)(kv + (size_t)(b * 256 + t * 128 + row) * 1024 + h * 64 + d4);
      tile[row * 65 + d4 + 0] = v.x; tile[row * 65 + d4 + 1] = v.y;
      tile[row * 65 + d4 + 2] = v.z; tile[row * 65 + d4 + 3] = v.w;
    }
    __syncthreads();
#pragma unroll
    for (int kk = 0; kk < 16; ++kk) {
      const float* kp = &tile[(kk * 8 + g) * 65];  // interleaved k-assignment
      float a = 0.f;
#pragma unroll
      for (int d = 0; d < 64; ++d) a += qreg[d] * kp[d];
      a *= 0.125f;  // dh^-0.5
      s[t * 16 + kk] = a;
      mx = fmaxf(mx, a);
    }
    __syncthreads();
  }
  // softmax across the 8 lanes sharing a row (low 3 lane bits = g)
#pragma unroll
  for (int o = 1; o < 8; o <<= 1) mx = fmaxf(mx, __shfl_xor(mx, o));
  float l = 0.f;
#pragma unroll
  for (int i = 0; i < 32; ++i) {
    s[i] = __expf(s[i] - mx);
    l += s[i];
  }
#pragma unroll
  for (int o = 1; o < 8; o <<= 1) l += __shfl_xor(l, o);
  float inv = 1.0f / l;
#pragma unroll
  for (int i = 0; i < 32; ++i) s[i] *= inv;

  float o_[64];
#pragma unroll
  for (int d = 0; d < 64; ++d) o_[d] = 0.f;
#pragma unroll
  for (int t = 0; t < 2; ++t) {
    // load V tile
#pragma unroll
    for (int i = 0; i < 8; ++i) {
      int idx = tid + i * 256;
      int row = idx >> 4, d4 = (idx & 15) << 2;
      float4 v = *(const float4*)(kv + (size_t)(b * 256 + t * 128 + row) * 1024 + 512 + h * 64 + d4);
      tile[row * 65 + d4 + 0] = v.x; tile[row * 65 + d4 + 1] = v.y;
      tile[row * 65 + d4 + 2] = v.z; tile[row * 65 + d4 + 3] = v.w;
    }
    __syncthreads();
#pragma unroll
    for (int kk = 0; kk < 16; ++kk) {
      float p = s[t * 16 + kk];
      const float* vp = &tile[(kk * 8 + g) * 65];
#pragma unroll
      for (int d = 0; d < 64; ++d) o_[d] += p * vp[d];
    }
    __syncthreads();
  }
  // reduce over the 8 k-groups
#pragma unroll
  for (int d = 0; d < 64; ++d) {
    o_[d] += __shfl_xor(o_[d], 1);
    o_[d] += __shfl_xor(o_[d], 2);
    o_[d] += __shfl_xor(o_[d], 4);
  }
  // every thread writes its g-slice (butterfly left full sum in all lanes)
#pragma unroll
  for (int j = 0; j < 8; ++j) qs[r * 64 + g * 8 + j] = o_[g * 8 + j];
  __syncthreads();
#pragma unroll
  for (int i = 0; i < 2; ++i) {
    int idx = tid + i * 256;
    int rr = idx >> 4, d4 = (idx & 15) << 2;
    *(float4*)(out + (size_t)(b * 4096 + n0 + rr) * 512 + h * 64 + d4) =
        *(float4*)&qs[rr * 64 + d4];
  }
}

// ---------------- launch ----------------
extern "C" void kernel_launch(void* const* d_in, const int* in_sizes, int n_in,
                              void* d_out, int out_size, void* d_ws, size_t ws_size,
                              hipStream_t stream) {
  const float* x     = (const float*)d_in[0];
  const float* Wq    = (const float*)d_in[1];
  const float* bq    = (const float*)d_in[2];
  const float* Wk    = (const float*)d_in[3];
  const float* bk    = (const float*)d_in[4];
  const float* Wv    = (const float*)d_in[5];
  const float* bv    = (const float*)d_in[6];
  const float* Wp    = (const float*)d_in[7];
  const float* bp    = (const float*)d_in[8];
  const float* Wsr   = (const float*)d_in[9];
  const float* bsr   = (const float*)d_in[10];
  const float* gamma = (const float*)d_in[11];
  const float* beta  = (const float*)d_in[12];

  float* ws     = (float*)d_ws;
  float* WqT    = ws;                  // 262144
  float* WpT    = WqT + 262144;        // 262144
  float* WkvT   = WpT + 262144;        // 524288  [512][1024]
  float* bkv    = WkvT + 524288;       // 1024
  float* xkv    = bkv + 1024;          // 524288  [1024][512]
  float* kvb    = xkv + 524288;        // 1048576 [1024][1024]
  float* attno  = kvb + 1048576;       // 8388608 [16384][512]
  float* shared = attno + 8388608;     // 8388608: conv partials, then reused as qbuf
  float* conv_part = shared;
  float* qbuf      = shared;
  float* outp = (float*)d_out;

  prep_weights_kernel<<<dim3(16, 16, 4), dim3(32, 8), 0, stream>>>(
      Wq, Wk, Wv, Wp, WqT, WpT, WkvT);
  concat_bias_kernel<<<1, 512, 0, stream>>>(bk, bv, bkv);
  // conv partials: grid (N-tiles=4, M-tiles=8, 16 (kh,kw) chunks)
  conv_gemm_kernel<<<dim3(4, 8, 16), 256, 0, stream>>>(x, Wsr, conv_part);
  ln_kernel<<<1024, 256, 0, stream>>>(conv_part, bsr, gamma, beta, xkv);
  // K/V projection fused: [1024,512] @ [512,1024] + bkv
  sgemm64_kernel<<<dim3(16, 16), 256, 0, stream>>>(xkv, WkvT, bkv, kvb, 1024, 1024, 512);
  // Q projection (reuses conv_part space — conv partials already consumed)
  sgemm128_kernel<<<dim3(4, 128), 256, 0, stream>>>(x, WqT, bq, qbuf, 16384, 512, 512);
  attn_kernel<<<dim3(128, 8, 4), 256, 0, stream>>>(qbuf, kvb, attno);
  // output projection -> d_out
  sgemm128_kernel<<<dim3(4, 128), 256, 0, stream>>>(attno, WpT, bp, outp, 16384, 512, 512);
}

// Round 2
// 681.928 us; speedup vs baseline: 5.1702x; 5.1702x over previous
//
#include <hip/hip_runtime.h>

// Problem constants
// B=4, H=W=64, N=4096, C=512, HEAD=8, dh=64, SR=4, Nk=256

// ---------------- weight prep: WqT, WpT, WkvT (=[Wk^T | Wv^T]) ----------------
__global__ void prep_weights_kernel(const float* __restrict__ Wq,
                                    const float* __restrict__ Wk,
                                    const float* __restrict__ Wv,
                                    const float* __restrict__ Wp,
                                    float* __restrict__ WqT,
                                    float* __restrict__ WpT,
                                    float* __restrict__ WkvT) {
  __shared__ float t[32][33];
  int z = blockIdx.z;
  const float* src = (z == 0) ? Wq : (z == 1) ? Wp : (z == 2) ? Wk : Wv;
  int n0 = blockIdx.y * 32, k0 = blockIdx.x * 32;
  int tx = threadIdx.x, ty = threadIdx.y;  // 32 x 8
#pragma unroll
  for (int i = 0; i < 32; i += 8)
    t[ty + i][tx] = src[(size_t)(n0 + ty + i) * 512 + k0 + tx];
  __syncthreads();
  float* dst = (z == 0) ? WqT : (z == 1) ? WpT : WkvT;
  int stride = (z < 2) ? 512 : 1024;
  int off = (z == 3) ? 512 : 0;
#pragma unroll
  for (int i = 0; i < 32; i += 8)
    dst[(size_t)(k0 + ty + i) * stride + off + n0 + tx] = t[tx][ty + i];
}

__global__ void concat_bias_kernel(const float* __restrict__ bk,
                                   const float* __restrict__ bv,
                                   float* __restrict__ bkv) {
  int t = threadIdx.x;  // 512
  bkv[t] = bk[t];
  bkv[512 + t] = bv[t];
}

// ---------------- fp32 SGEMM, 128x128 tile, BK=16, 256 thr, 8x8 micro ----------------
__global__ __launch_bounds__(256) void sgemm128_kernel(
    const float* __restrict__ A, const float* __restrict__ B,
    const float* __restrict__ bias, float* __restrict__ C,
    int M, int N, int K) {
  __shared__ __align__(16) float As[16][132];  // [k][m], padded
  __shared__ __align__(16) float Bs[16][128];  // [k][n]
  int tid = threadIdx.x;
  int bx = blockIdx.x, by = blockIdx.y;
  int tx = tid & 15, ty = tid >> 4;
  float acc[2][2][4][4] = {};
  for (int k0 = 0; k0 < K; k0 += 16) {
#pragma unroll
    for (int i = 0; i < 2; ++i) {
      int idx = tid + i * 256;
      int m = idx >> 2, kq = (idx & 3) << 2;
      float4 a = *(const float4*)(A + (size_t)(by * 128 + m) * K + k0 + kq);
      As[kq + 0][m] = a.x; As[kq + 1][m] = a.y;
      As[kq + 2][m] = a.z; As[kq + 3][m] = a.w;
    }
#pragma unroll
    for (int i = 0; i < 2; ++i) {
      int idx = tid + i * 256;
      int k = idx >> 5, n4 = (idx & 31) << 2;
      *(float4*)&Bs[k][n4] = *(const float4*)(B + (size_t)(k0 + k) * N + bx * 128 + n4);
    }
    __syncthreads();
#pragma unroll
    for (int k = 0; k < 16; ++k) {
      float4 a0 = *(float4*)&As[k][ty * 4];
      float4 a1 = *(float4*)&As[k][64 + ty * 4];
      float4 b0 = *(float4*)&Bs[k][tx * 4];
      float4 b1 = *(float4*)&Bs[k][64 + tx * 4];
      float av[2][4] = {{a0.x, a0.y, a0.z, a0.w}, {a1.x, a1.y, a1.z, a1.w}};
      float bv[2][4] = {{b0.x, b0.y, b0.z, b0.w}, {b1.x, b1.y, b1.z, b1.w}};
#pragma unroll
      for (int qr = 0; qr < 2; ++qr)
#pragma unroll
        for (int i = 0; i < 4; ++i)
#pragma unroll
          for (int qc = 0; qc < 2; ++qc)
#pragma unroll
            for (int j = 0; j < 4; ++j)
              acc[qr][qc][i][j] += av[qr][i] * bv[qc][j];
    }
    __syncthreads();
  }
#pragma unroll
  for (int qr = 0; qr < 2; ++qr)
#pragma unroll
    for (int i = 0; i < 4; ++i) {
      int row = by * 128 + qr * 64 + ty * 4 + i;
#pragma unroll
      for (int qc = 0; qc < 2; ++qc) {
        int col = bx * 128 + qc * 64 + tx * 4;
        float4 bb = *(const float4*)(bias + col);
        float4 o;
        o.x = acc[qr][qc][i][0] + bb.x;
        o.y = acc[qr][qc][i][1] + bb.y;
        o.z = acc[qr][qc][i][2] + bb.z;
        o.w = acc[qr][qc][i][3] + bb.w;
        *(float4*)(C + (size_t)row * N + col) = o;
      }
    }
}

// ---------------- fp32 SGEMM, 64x64 tile (for the small K/V projection) ----------------
__global__ __launch_bounds__(256) void sgemm64_kernel(
    const float* __restrict__ A, const float* __restrict__ B,
    const float* __restrict__ bias, float* __restrict__ C,
    int M, int N, int K) {
  __shared__ __align__(16) float As[16][68];
  __shared__ __align__(16) float Bs[16][64];
  int tid = threadIdx.x;
  int bx = blockIdx.x, by = blockIdx.y;
  int tx = tid & 15, ty = tid >> 4;
  float acc[4][4] = {};
  for (int k0 = 0; k0 < K; k0 += 16) {
    {
      int m = tid >> 2, kq = (tid & 3) << 2;
      float4 a = *(const float4*)(A + (size_t)(by * 64 + m) * K + k0 + kq);
      As[kq + 0][m] = a.x; As[kq + 1][m] = a.y;
      As[kq + 2][m] = a.z; As[kq + 3][m] = a.w;
    }
    {
      int k = tid >> 4, n4 = (tid & 15) << 2;
      *(float4*)&Bs[k][n4] = *(const float4*)(B + (size_t)(k0 + k) * N + bx * 64 + n4);
    }
    __syncthreads();
#pragma unroll
    for (int k = 0; k < 16; ++k) {
      float4 a0 = *(float4*)&As[k][ty * 4];
      float4 b0 = *(float4*)&Bs[k][tx * 4];
      float av[4] = {a0.x, a0.y, a0.z, a0.w};
      float bv[4] = {b0.x, b0.y, b0.z, b0.w};
#pragma unroll
      for (int i = 0; i < 4; ++i)
#pragma unroll
        for (int j = 0; j < 4; ++j) acc[i][j] += av[i] * bv[j];
    }
    __syncthreads();
  }
#pragma unroll
  for (int i = 0; i < 4; ++i) {
    int row = by * 64 + ty * 4 + i;
    int col = bx * 64 + tx * 4;
    float4 bb = *(const float4*)(bias + col);
    float4 o;
    o.x = acc[i][0] + bb.x; o.y = acc[i][1] + bb.y;
    o.z = acc[i][2] + bb.z; o.w = acc[i][3] + bb.w;
    *(float4*)(C + (size_t)row * N + col) = o;
  }
}

// ---------------- conv as split-K GEMM: one (kh,kw) chunk per blockIdx.z ----------------
// M=1024 patches, K=512 (ci), N=512 (co). Writes partials [16][1024][512].
__global__ __launch_bounds__(256) void conv_gemm_kernel(
    const float* __restrict__ x, const float* __restrict__ Wsr,
    float* __restrict__ part) {
  __shared__ __align__(16) float As[16][132];
  __shared__ __align__(16) float Bs[16][128];
  int tid = threadIdx.x;
  int bx = blockIdx.x, by = blockIdx.y, z = blockIdx.z;
  int kh = z >> 2, kw = z & 3;
  int tx = tid & 15, ty = tid >> 4;
  int ml[2];
  size_t abase[2];
#pragma unroll
  for (int i = 0; i < 2; ++i) {
    int idx = tid + i * 256;
    int m = idx >> 2;
    int gm = by * 128 + m;
    int b = gm >> 8, rem = gm & 255, oh = rem >> 4, ow = rem & 15;
    abase[i] = (size_t)(b * 4096 + (oh * 4 + kh) * 64 + ow * 4 + kw) * 512;
    ml[i] = m;
  }
  const float* Wbase = Wsr + (size_t)z * 512 * 512;
  float acc[2][2][4][4] = {};
  for (int k0 = 0; k0 < 512; k0 += 16) {
#pragma unroll
    for (int i = 0; i < 2; ++i) {
      int idx = tid + i * 256;
      int kq = (idx & 3) << 2;
      float4 a = *(const float4*)(x + abase[i] + k0 + kq);
      As[kq + 0][ml[i]] = a.x; As[kq + 1][ml[i]] = a.y;
      As[kq + 2][ml[i]] = a.z; As[kq + 3][ml[i]] = a.w;
    }
#pragma unroll
    for (int i = 0; i < 2; ++i) {
      int idx = tid + i * 256;
      int k = idx >> 5, n4 = (idx & 31) << 2;
      *(float4*)&Bs[k][n4] =
          *(const float4*)(Wbase + (size_t)(k0 + k) * 512 + bx * 128 + n4);
    }
    __syncthreads();
#pragma unroll
    for (int k = 0; k < 16; ++k) {
      float4 a0 = *(float4*)&As[k][ty * 4];
      float4 a1 = *(float4*)&As[k][64 + ty * 4];
      float4 b0 = *(float4*)&Bs[k][tx * 4];
      float4 b1 = *(float4*)&Bs[k][64 + tx * 4];
      float av[2][4] = {{a0.x, a0.y, a0.z, a0.w}, {a1.x, a1.y, a1.z, a1.w}};
      float bv[2][4] = {{b0.x, b0.y, b0.z, b0.w}, {b1.x, b1.y, b1.z, b1.w}};
#pragma unroll
      for (int qr = 0; qr < 2; ++qr)
#pragma unroll
        for (int i = 0; i < 4; ++i)
#pragma unroll
          for (int qc = 0; qc < 2; ++qc)
#pragma unroll
            for (int j = 0; j < 4; ++j)
              acc[qr][qc][i][j] += av[qr][i] * bv[qc][j];
    }
    __syncthreads();
  }
  float* Cp = part + (size_t)z * 1024 * 512;
#pragma unroll
  for (int qr = 0; qr < 2; ++qr)
#pragma unroll
    for (int i = 0; i < 4; ++i) {
      int row = by * 128 + qr * 64 + ty * 4 + i;
#pragma unroll
      for (int qc = 0; qc < 2; ++qc) {
        int col = bx * 128 + qc * 64 + tx * 4;
        float4 o;
        o.x = acc[qr][qc][i][0]; o.y = acc[qr][qc][i][1];
        o.z = acc[qr][qc][i][2]; o.w = acc[qr][qc][i][3];
        *(float4*)(Cp + (size_t)row * 512 + col) = o;
      }
    }
}

// ---------------- partial-sum + bias + LayerNorm ----------------
__global__ __launch_bounds__(256) void ln_kernel(
    const float* __restrict__ part, const float* __restrict__ bsr,
    const float* __restrict__ gamma, const float* __restrict__ beta,
    float* __restrict__ xkv) {
  int row = blockIdx.x;  // 0..1023
  int t = threadIdx.x;   // 256
  float v0 = bsr[t], v1 = bsr[t + 256];
  for (int p = 0; p < 16; ++p) {
    v0 += part[(size_t)p * 524288 + (size_t)row * 512 + t];
    v1 += part[(size_t)p * 524288 + (size_t)row * 512 + t + 256];
  }
  float s = v0 + v1, sq = v0 * v0 + v1 * v1;
#pragma unroll
  for (int o = 1; o < 64; o <<= 1) {
    s += __shfl_xor(s, o);
    sq += __shfl_xor(sq, o);
  }
  __shared__ float red[8];
  int wv = t >> 6;
  if ((t & 63) == 0) { red[wv] = s; red[4 + wv] = sq; }
  __syncthreads();
  s = red[0] + red[1] + red[2] + red[3];
  sq = red[4] + red[5] + red[6] + red[7];
  float mu = s * (1.0f / 512.0f);
  float var = sq * (1.0f / 512.0f) - mu * mu;
  float rs = rsqrtf(var + 1e-5f);
  xkv[(size_t)row * 512 + t] = (v0 - mu) * rs * gamma[t] + beta[t];
  xkv[(size_t)row * 512 + t + 256] = (v1 - mu) * rs * gamma[t + 256] + beta[t + 256];
}

// ---------------- fused attention v2: no spills, online softmax ----------------
// Block = (b, h, 64 q-rows). 256 threads = 16 ty x 16 tx.
// Thread owns rows r(i) = ty + 16*i (row-strided: LDS row reads land on
// bank (4*ty)%32 -> 2-way aliasing, free), k-slots tx+16j (scores),
// d-slice tx*4 (PV/output). Online softmax over 4 k-quarters of 64.
// Per-thread state: m[4], l[4], o[4][4], s[4][4]  (~56 floats, no spill).
__global__ __launch_bounds__(256) void attn_kernel(
    const float* __restrict__ q, const float* __restrict__ kv,
    float* __restrict__ out) {
  __shared__ __align__(16) float qs[64 * 68];  // q rows (pre-scaled)
  __shared__ __align__(16) float Ks[64 * 68];  // K quarter [k][d]
  __shared__ __align__(16) float Vs[64 * 68];  // V quarter [k][d]
  __shared__ __align__(16) float ps[64 * 68];  // p quarter [r][k]
  int tid = threadIdx.x;
  int qt = blockIdx.x, h = blockIdx.y, b = blockIdx.z;
  int n0 = qt * 64;
  int ty = tid >> 4, tx = tid & 15;

  // load q tile [64][64], scaled by dh^-0.5
#pragma unroll
  for (int i = 0; i < 4; ++i) {
    int idx = tid + i * 256;
    int r = idx >> 4, c4 = (idx & 15) << 2;
    float4 v = *(const float4*)(q + (size_t)(b * 4096 + n0 + r) * 512 + h * 64 + c4);
    v.x *= 0.125f; v.y *= 0.125f; v.z *= 0.125f; v.w *= 0.125f;
    *(float4*)&qs[r * 68 + c4] = v;
  }

  float m[4], l[4], o[4][4];
#pragma unroll
  for (int i = 0; i < 4; ++i) {
    m[i] = -1e30f; l[i] = 0.f;
#pragma unroll
    for (int j = 0; j < 4; ++j) o[i][j] = 0.f;
  }

  for (int qtr = 0; qtr < 4; ++qtr) {
    __syncthreads();  // guard Ks/Vs/ps overwrite (iter 0: no-op cost)
#pragma unroll
    for (int i = 0; i < 4; ++i) {
      int idx = tid + i * 256;
      int kr = idx >> 4, c4 = (idx & 15) << 2;
      const float* src = kv + (size_t)(b * 256 + qtr * 64 + kr) * 1024 + h * 64 + c4;
      *(float4*)&Ks[kr * 68 + c4] = *(const float4*)src;
      *(float4*)&Vs[kr * 68 + c4] = *(const float4*)(src + 512);
    }
    __syncthreads();

    // scores: s[i][j] = q[row ty+16i] . K[tx+16j]
    float s[4][4] = {};
#pragma unroll
    for (int d4 = 0; d4 < 16; ++d4) {
      float4 kf[4];
#pragma unroll
      for (int j = 0; j < 4; ++j)
        kf[j] = *(float4*)&Ks[(tx + 16 * j) * 68 + d4 * 4];
#pragma unroll
      for (int i = 0; i < 4; ++i) {
        float4 qf = *(float4*)&qs[(ty + 16 * i) * 68 + d4 * 4];
#pragma unroll
        for (int j = 0; j < 4; ++j)
          s[i][j] += qf.x * kf[j].x + qf.y * kf[j].y + qf.z * kf[j].z + qf.w * kf[j].w;
      }
    }

    // online softmax update; write unnormalized p to LDS
#pragma unroll
    for (int i = 0; i < 4; ++i) {
      float qm = fmaxf(fmaxf(s[i][0], s[i][1]), fmaxf(s[i][2], s[i][3]));
#pragma unroll
      for (int d = 1; d < 16; d <<= 1) qm = fmaxf(qm, __shfl_xor(qm, d));
      float nm = fmaxf(m[i], qm);
      float f = __expf(m[i] - nm);
      float p0 = __expf(s[i][0] - nm);
      float p1 = __expf(s[i][1] - nm);
      float p2 = __expf(s[i][2] - nm);
      float p3 = __expf(s[i][3] - nm);
      float sum = p0 + p1 + p2 + p3;
#pragma unroll
      for (int d = 1; d < 16; d <<= 1) sum += __shfl_xor(sum, d);
      l[i] = l[i] * f + sum;
      m[i] = nm;
      o[i][0] *= f; o[i][1] *= f; o[i][2] *= f; o[i][3] *= f;
      float* pr = &ps[(ty + 16 * i) * 68];
      pr[tx] = p0; pr[tx + 16] = p1; pr[tx + 32] = p2; pr[tx + 48] = p3;
    }
    __syncthreads();

    // PV: o[i][0..3] += sum_k p[row][k] * V[k][tx*4 .. +3]
#pragma unroll
    for (int kc = 0; kc < 16; ++kc) {
      float4 vf[4];
#pragma unroll
      for (int j = 0; j < 4; ++j)
        vf[j] = *(float4*)&Vs[(kc * 4 + j) * 68 + tx * 4];
#pragma unroll
      for (int i = 0; i < 4; ++i) {
        float4 pf = *(float4*)&ps[(ty + 16 * i) * 68 + kc * 4];
        o[i][0] += pf.x * vf[0].x + pf.y * vf[1].x + pf.z * vf[2].x + pf.w * vf[3].x;
        o[i][1] += pf.x * vf[0].y + pf.y * vf[1].y + pf.z * vf[2].y + pf.w * vf[3].y;
        o[i][2] += pf.x * vf[0].z + pf.y * vf[1].z + pf.z * vf[2].z + pf.w * vf[3].z;
        o[i][3] += pf.x * vf[0].w + pf.y * vf[1].w + pf.z * vf[2].w + pf.w * vf[3].w;
      }
    }
  }

  // normalize + store
#pragma unroll
  for (int i = 0; i < 4; ++i) {
    float inv = 1.0f / l[i];
    float4 ov;
    ov.x = o[i][0] * inv; ov.y = o[i][1] * inv;
    ov.z = o[i][2] * inv; ov.w = o[i][3] * inv;
    *(float4*)(out + (size_t)(b * 4096 + n0 + ty + 16 * i) * 512 + h * 64 + tx * 4) = ov;
  }
}

// ---------------- launch ----------------
extern "C" void kernel_launch(void* const* d_in, const int* in_sizes, int n_in,
                              void* d_out, int out_size, void* d_ws, size_t ws_size,
                              hipStream_t stream) {
  const float* x     = (const float*)d_in[0];
  const float* Wq    = (const float*)d_in[1];
  const float* bq    = (const float*)d_in[2];
  const float* Wk    = (const float*)d_in[3];
  const float* bk    = (const float*)d_in[4];
  const float* Wv    = (const float*)d_in[5];
  const float* bv    = (const float*)d_in[6];
  const float* Wp    = (const float*)d_in[7];
  const float* bp    = (const float*)d_in[8];
  const float* Wsr   = (const float*)d_in[9];
  const float* bsr   = (const float*)d_in[10];
  const float* gamma = (const float*)d_in[11];
  const float* beta  = (const float*)d_in[12];

  float* ws     = (float*)d_ws;
  float* WqT    = ws;                  // 262144
  float* WpT    = WqT + 262144;        // 262144
  float* WkvT   = WpT + 262144;        // 524288  [512][1024]
  float* bkv    = WkvT + 524288;       // 1024
  float* xkv    = bkv + 1024;          // 524288  [1024][512]
  float* kvb    = xkv + 524288;        // 1048576 [1024][1024]
  float* attno  = kvb + 1048576;       // 8388608 [16384][512]
  float* shared = attno + 8388608;     // 8388608: conv partials, then reused as qbuf
  float* conv_part = shared;
  float* qbuf      = shared;
  float* outp = (float*)d_out;

  prep_weights_kernel<<<dim3(16, 16, 4), dim3(32, 8), 0, stream>>>(
      Wq, Wk, Wv, Wp, WqT, WpT, WkvT);
  concat_bias_kernel<<<1, 512, 0, stream>>>(bk, bv, bkv);
  // conv partials: grid (N-tiles=4, M-tiles=8, 16 (kh,kw) chunks)
  conv_gemm_kernel<<<dim3(4, 8, 16), 256, 0, stream>>>(x, Wsr, conv_part);
  ln_kernel<<<1024, 256, 0, stream>>>(conv_part, bsr, gamma, beta, xkv);
  // K/V projection fused: [1024,512] @ [512,1024] + bkv
  sgemm64_kernel<<<dim3(16, 16), 256, 0, stream>>>(xkv, WkvT, bkv, kvb, 1024, 1024, 512);
  // Q projection (reuses conv_part space — conv partials already consumed)
  sgemm128_kernel<<<dim3(4, 128), 256, 0, stream>>>(x, WqT, bq, qbuf, 16384, 512, 512);
  attn_kernel<<<dim3(64, 8, 4), 256, 0, stream>>>(qbuf, kvb, attno);
  // output projection -> d_out
  sgemm128_kernel<<<dim3(4, 128), 256, 0, stream>>>(attno, WpT, bp, outp, 16384, 512, 512);
}